// Round 16
// baseline (4311.647 us; speedup 1.0000x reference)
//
#include <hip/hip_runtime.h>
#include <hip/hip_bf16.h>
#include <stdint.h>

#define BATCH 64
#define SEQ   512
#define INDIM 1024
#define HDIM  1024
#define NBLK  128
#define NGRP  8       // 8 groups x 8 batch rows
#define GSLOT 64      // blocks per group, 16 hidden cols each
#define FPAD  16      // 64 B per flag
#define SLAB_DW 8192  // dwords per (group,buf): 8 rows x 1024 K (hi|lo<<16)

typedef short bf16x8 __attribute__((ext_vector_type(8)));
typedef short s16x4  __attribute__((ext_vector_type(4)));
typedef float f32x2  __attribute__((ext_vector_type(2)));
typedef float f32x4  __attribute__((ext_vector_type(4)));
typedef unsigned short u16;
typedef unsigned int   u32;
typedef u32 u32x2 __attribute__((ext_vector_type(2)));
typedef u32 u32x4 __attribute__((ext_vector_type(4)));
typedef u16 u16x4 __attribute__((ext_vector_type(4)));

static __device__ __forceinline__ u16 f2bf(float x) {
  unsigned int u = __float_as_uint(x);
  u += 0x7fffu + ((u >> 16) & 1u);
  return (u16)(u >> 16);
}
static __device__ __forceinline__ float bf2f(u16 b) {
  return __uint_as_float(((unsigned int)b) << 16);
}

// device-coherent scalar load — proven flag-poll primitive (r9/r15)
static __device__ __forceinline__ int coh_ld_i32(const int* p) {
  int v;
  asm volatile("global_load_dword %0, %1, off sc0 sc1\n\t"
               "s_waitcnt vmcnt(0)"
               : "=&v"(v) : "v"(p) : "memory");
  return v;
}

static __device__ __forceinline__ void split4(float4 v, u16x4& hi, u16x4& lo) {
  hi.x = f2bf(v.x); lo.x = f2bf(v.x - bf2f(hi.x));
  hi.y = f2bf(v.y); lo.y = f2bf(v.y - bf2f(hi.y));
  hi.z = f2bf(v.z); lo.z = f2bf(v.z - bf2f(hi.z));
  hi.w = f2bf(v.w); lo.w = f2bf(v.w - bf2f(hi.w));
}
static __device__ __forceinline__ bf16x8 ld8(const u16* p) {
  s16x4 a = *(const s16x4*)p;
  s16x4 b = *(const s16x4*)(p + 4);
  return __builtin_shufflevector(a, b, 0, 1, 2, 3, 4, 5, 6, 7);
}

// ---- init0: zero flags ----
__global__ void init0(int* __restrict__ flags, int n) {
  int i = blockIdx.x * blockDim.x + threadIdx.x;
  if (i < n) flags[i] = 0;
}

// ---- init1: pack h0 into buf0 slabs, dword = hi | lo<<16 ----
// group g = rows [8g,8g+8). dword idx k32*256 + (kg*8 + r)*8 + j holds
// h[8g+r][k32*32 + kg*8 + j].
__global__ void init1(const float* __restrict__ h0, u32* __restrict__ hw) {
  int i = blockIdx.x * blockDim.x + threadIdx.x;
  if (i < BATCH * HDIM) {
    int b = i >> 10, k = i & 1023;
    int g = b >> 3, r = b & 7;
    int k32 = k >> 5, kg = (k >> 3) & 3, j = k & 7;
    float x = h0[i];
    u16 hi = f2bf(x);
    u16 lo = f2bf(x - bf2f(hi));
    size_t di = (size_t)(g * 2) * SLAB_DW + (size_t)(k32 * 256 + (kg * 8 + r) * 8 + j);
    hw[di] = (u32)hi | ((u32)lo << 16);
  }
}

// ---- xproj: xp = X @ Wih^T + bih + bhh via split-bf16 MFMA (into out) ----
__global__ __launch_bounds__(256) void xproj_kernel(const float* __restrict__ A,
                                                    const float* __restrict__ W,
                                                    const float* __restrict__ bih,
                                                    const float* __restrict__ bhh,
                                                    float* __restrict__ C) {
  __shared__ u16 Ah[4][128][12], Al[4][128][12], Bh[4][128][12], Bl[4][128][12];
  const int nb = blockIdx.x;
  const int mb = blockIdx.y;
  const int m_base = mb * 128, n_base = nb * 128;
  const int tid = (int)threadIdx.x;
  const int wid = tid >> 6, lane = tid & 63;
  const int wm = wid >> 1, wn = wid & 1;
  const int r = lane & 15, kg = lane >> 4;
  const int srow = tid >> 1;
  const int skq  = (tid & 1) * 16;

  const float* ap0 = A + (size_t)(m_base + srow) * INDIM + skq;
  const float* bp0 = W + (size_t)(n_base + srow) * INDIM + skq;

  f32x4 acc[4][4] = {};

  for (int k0 = 0; k0 < INDIM; k0 += 32) {
    float4 av[4], bv[4];
#pragma unroll
    for (int i = 0; i < 4; ++i) {
      av[i] = *(const float4*)(ap0 + k0 + i * 4);
      bv[i] = *(const float4*)(bp0 + k0 + i * 4);
    }
    __syncthreads();
#pragma unroll
    for (int i = 0; i < 4; ++i) {
      int kk = skq + i * 4;
      int kgw = kk >> 3, off = kk & 7;
      u16x4 hi, lo;
      split4(av[i], hi, lo);
      *(u16x4*)&Ah[kgw][srow][off] = hi;
      *(u16x4*)&Al[kgw][srow][off] = lo;
      split4(bv[i], hi, lo);
      *(u16x4*)&Bh[kgw][srow][off] = hi;
      *(u16x4*)&Bl[kgw][srow][off] = lo;
    }
    __syncthreads();

    bf16x8 ah[4], al[4], bhv[4], blv[4];
#pragma unroll
    for (int mf = 0; mf < 4; ++mf) {
      int row = wm * 64 + mf * 16 + r;
      ah[mf] = ld8(&Ah[kg][row][0]);
      al[mf] = ld8(&Al[kg][row][0]);
    }
#pragma unroll
    for (int nf = 0; nf < 4; ++nf) {
      int row = wn * 64 + nf * 16 + r;
      bhv[nf] = ld8(&Bh[kg][row][0]);
      blv[nf] = ld8(&Bl[kg][row][0]);
    }
#pragma unroll
    for (int mf = 0; mf < 4; ++mf)
#pragma unroll
      for (int nf = 0; nf < 4; ++nf) {
        acc[mf][nf] = __builtin_amdgcn_mfma_f32_16x16x32_bf16(ah[mf], bhv[nf], acc[mf][nf], 0, 0, 0);
        acc[mf][nf] = __builtin_amdgcn_mfma_f32_16x16x32_bf16(ah[mf], blv[nf], acc[mf][nf], 0, 0, 0);
        acc[mf][nf] = __builtin_amdgcn_mfma_f32_16x16x32_bf16(al[mf], bhv[nf], acc[mf][nf], 0, 0, 0);
      }
  }

#pragma unroll
  for (int nf = 0; nf < 4; ++nf) {
    int col = n_base + wn * 64 + nf * 16 + r;
    float bias = bih[col] + bhh[col];
#pragma unroll
    for (int mf = 0; mf < 4; ++mf) {
      int rowb = m_base + wm * 64 + mf * 16 + kg * 4;
#pragma unroll
      for (int q = 0; q < 4; ++q) {
        C[(size_t)(rowb + q) * HDIM + col] = acc[mf][nf][q] + bias;
      }
    }
  }
}

// ---- scan: quad-group time-interleave. 128 blocks x 576 threads. ----
// Block b: quad q = b>>6 (groups 4q..4q+3), slot = b&63 (cols [16s,16s+16)).
// Per iteration: 4 phases (one group-step each). Waves 0-7: consumers
// (K=128 each; all-64-lane flag poll). Wave j does group-j epi (rotating).
// Wave 8: all HBM I/O. Exchange chain hides under 3 other phases.
__global__ __launch_bounds__(576, 1) void rnn_scan(
    const float* __restrict__ Whh, float* __restrict__ out,
    u32* ring, int* flags) {
  __shared__ u16 WH[32][64][8], WL[32][64][8];       // 64 KB
  __shared__ __align__(16) float red[4][8][8][18];   // 18 KB
  __shared__ __align__(8) float xfbuf[4][2][8][16];  // 4 KB
  __shared__ __align__(8) float sbuf[4][2][8][16];   // 4 KB

  const int blk = (int)blockIdx.x;
  const int q = blk >> 6;
  const int slot = blk & 63;
  const int n0 = slot * 16;
  const int tid = (int)threadIdx.x;
  const int wv = tid >> 6, lane = tid & 63;
  const int r = lane & 15, kg = lane >> 4;
  const bool zrow = r >= 8;

  // ---- one-time: stage Whh rows n0..n0+15 into LDS, fragment-major, hi/lo ----
  for (int f4 = tid; f4 < 4096; f4 += 576) {
    int row = f4 >> 8;                  // 0..15 (local col)
    int k0 = (f4 & 255) * 4;
    float4 v = *(const float4*)(Whh + (size_t)(n0 + row) * HDIM + k0);
    int k32 = k0 >> 5, kgg = (k0 >> 3) & 3, jj = k0 & 7;
    int ln = kgg * 16 + row;
    u16x4 hi, lo;
    split4(v, hi, lo);
    *(u16x4*)&WH[k32][ln][jj] = hi;
    *(u16x4*)&WL[k32][ln][jj] = lo;
  }

  // epi / I/O geometry: lane -> (row er 0..7, even col ec 0..14)
  const int er = lane >> 3;
  const int ec = (lane & 7) * 2;

  // wave8: preload xp(0) for the 4 groups
  if (wv == 8) {
#pragma unroll
    for (int j = 0; j < 4; ++j) {
      int g = q * 4 + j;
      f32x2 xv = *(const f32x2*)(out + ((size_t)(g * 8 + er) * SEQ) * HDIM + n0 + ec);
      *(f32x2*)&xfbuf[j][0][er][ec] = xv;
    }
  }
  __syncthreads();

  for (int t = 0; t < SEQ; ++t) {
    const int pb = t & 1;
#pragma unroll
    for (int j = 0; j < 4; ++j) {
      const int g = q * 4 + j;
      if (wv < 8) {
        // ---- consumer: poll all 64 producer flags (1/lane), load, MFMA ----
        if (t > 0) {
          const int* fp = flags + (g * GSLOT + lane) * FPAD;
          int v;
          do { v = coh_ld_i32(fp); } while (!__all(v >= t));
        }
        u32x4 P0, P1, P2, P3, P4, P5, P6, P7;
        if (!zrow) {
          const char* a0 = (const char*)(ring + (size_t)(g * 2 + pb) * SLAB_DW)
                           + (size_t)(wv * 4096 + (kg * 8 + r) * 32);
          asm volatile(
              "global_load_dwordx4 %0, %8, off sc0 sc1\n\t"
              "global_load_dwordx4 %1, %8, off offset:16 sc0 sc1\n\t"
              "global_load_dwordx4 %2, %8, off offset:1024 sc0 sc1\n\t"
              "global_load_dwordx4 %3, %8, off offset:1040 sc0 sc1\n\t"
              "global_load_dwordx4 %4, %8, off offset:2048 sc0 sc1\n\t"
              "global_load_dwordx4 %5, %8, off offset:2064 sc0 sc1\n\t"
              "global_load_dwordx4 %6, %8, off offset:3072 sc0 sc1\n\t"
              "global_load_dwordx4 %7, %8, off offset:3088 sc0 sc1"
              : "=&v"(P0), "=&v"(P1), "=&v"(P2), "=&v"(P3),
                "=&v"(P4), "=&v"(P5), "=&v"(P6), "=&v"(P7)
              : "v"(a0)
              : "memory");
          asm volatile("s_waitcnt vmcnt(0)"
              : "+v"(P0), "+v"(P1), "+v"(P2), "+v"(P3),
                "+v"(P4), "+v"(P5), "+v"(P6), "+v"(P7));
        } else {
          P0 = P1 = P2 = P3 = P4 = P5 = P6 = P7 = (u32x4){0, 0, 0, 0};
        }

        f32x4 acc = {0.f, 0.f, 0.f, 0.f};
#define DO_K32(i, QA, QB)                                                      \
        {                                                                      \
          u32 d0 = QA[0], d1 = QA[1], d2 = QA[2], d3 = QA[3];                  \
          u32 d4 = QB[0], d5 = QB[1], d6 = QB[2], d7 = QB[3];                  \
          union { u32 w[4]; bf16x8 v; } AH, AL;                                \
          AH.w[0] = (d0 & 0xFFFFu) | (d1 << 16);                               \
          AH.w[1] = (d2 & 0xFFFFu) | (d3 << 16);                               \
          AH.w[2] = (d4 & 0xFFFFu) | (d5 << 16);                               \
          AH.w[3] = (d6 & 0xFFFFu) | (d7 << 16);                               \
          AL.w[0] = (d0 >> 16) | (d1 & 0xFFFF0000u);                           \
          AL.w[1] = (d2 >> 16) | (d3 & 0xFFFF0000u);                           \
          AL.w[2] = (d4 >> 16) | (d5 & 0xFFFF0000u);                           \
          AL.w[3] = (d6 >> 16) | (d7 & 0xFFFF0000u);                           \
          int k32 = wv * 4 + (i);                                              \
          bf16x8 bh = *(const bf16x8*)&WH[k32][lane][0];                       \
          bf16x8 bl = *(const bf16x8*)&WL[k32][lane][0];                       \
          acc = __builtin_amdgcn_mfma_f32_16x16x32_bf16(AH.v, bh, acc, 0, 0, 0); \
          acc = __builtin_amdgcn_mfma_f32_16x16x32_bf16(AH.v, bl, acc, 0, 0, 0); \
          acc = __builtin_amdgcn_mfma_f32_16x16x32_bf16(AL.v, bh, acc, 0, 0, 0); \
        }
        DO_K32(0, P0, P1)
        DO_K32(1, P2, P3)
        DO_K32(2, P4, P5)
        DO_K32(3, P6, P7)
#undef DO_K32

        // K-reduction scratch. D: col = lane&15, row = kg*4+qq (rows<8 only)
        if (kg < 2) {
#pragma unroll
          for (int qq = 0; qq < 4; ++qq) red[j][wv][kg * 4 + qq][r] = acc[qq];
        }
      } else {
        // ---- wave 8: HBM I/O for group j ----
        if (t >= 2) {
          f32x2 sv = *(const f32x2*)&sbuf[j][pb][er][ec];
          __builtin_nontemporal_store(sv,
              (f32x2*)(out + ((size_t)(g * 8 + er) * SEQ + (t - 2)) * HDIM + n0 + ec));
        }
        if (t + 1 < SEQ) {
          f32x2 xv = *(const f32x2*)(out + ((size_t)(g * 8 + er) * SEQ + (t + 1)) * HDIM + n0 + ec);
          *(f32x2*)&xfbuf[j][pb ^ 1][er][ec] = xv;
        }
      }
      __syncthreads();   // phase barrier

      if (wv == j) {
        // ---- epilogue for group j (rotating wave): LDS inputs only ----
        f32x2 s = *(const f32x2*)&xfbuf[j][pb][er][ec];
#pragma unroll
        for (int w = 0; w < 8; ++w) {
          s.x += red[j][w][er][ec];
          s.y += red[j][w][er][ec + 1];
        }
        s.x = s.x > 0.f ? s.x : 0.f;
        s.y = s.y > 0.f ? s.y : 0.f;
        *(f32x2*)&sbuf[j][pb][er][ec] = s;

        u16 h0 = f2bf(s.x), h1 = f2bf(s.y);
        u16 l0 = f2bf(s.x - bf2f(h0)), l1 = f2bf(s.y - bf2f(h1));
        u32x2 D = {(u32)h0 | ((u32)l0 << 16), (u32)h1 | ((u32)l1 << 16)};
        int cg = n0 + ec;
        u32* hp = ring + (size_t)(g * 2 + (pb ^ 1)) * SLAB_DW
                  + (size_t)((cg >> 5) * 256 + (((cg >> 3) & 3) * 8 + er) * 8 + (cg & 7));
        // agent-scope (MALL) store + ack, then system-scope flag (r15-proven)
        asm volatile("global_store_dwordx2 %0, %1, off sc1\n\t"
                     "s_waitcnt vmcnt(0)"
                     :: "v"(hp), "v"(D) : "memory");
        if (lane == 0) {
          int* fp = flags + (g * GSLOT + slot) * FPAD;
          int tv = t + 1;
          asm volatile("global_store_dword %0, %1, off sc0 sc1"
                       :: "v"(fp), "v"(tv) : "memory");
        }
      }
    }
  }

  // tail: out(SEQ-2) and out(SEQ-1)
  __syncthreads();
  if (wv == 8) {
#pragma unroll
    for (int j = 0; j < 4; ++j) {
      int g = q * 4 + j;
      f32x2 a = *(const f32x2*)&sbuf[j][(SEQ - 2) & 1][er][ec];
      __builtin_nontemporal_store(a,
          (f32x2*)(out + ((size_t)(g * 8 + er) * SEQ + (SEQ - 2)) * HDIM + n0 + ec));
      f32x2 b = *(const f32x2*)&sbuf[j][(SEQ - 1) & 1][er][ec];
      __builtin_nontemporal_store(b,
          (f32x2*)(out + ((size_t)(g * 8 + er) * SEQ + (SEQ - 1)) * HDIM + n0 + ec));
    }
  }
}

// ---- h_n = outputs[:, SEQ-1, :] ----
__global__ void copy_hn(const float* __restrict__ out, float* __restrict__ hn) {
  int idx = blockIdx.x * blockDim.x + threadIdx.x;
  if (idx < BATCH * HDIM) {
    int b = idx >> 10, j = idx & 1023;
    hn[idx] = out[((size_t)b * SEQ + (SEQ - 1)) * (size_t)HDIM + j];
  }
}

extern "C" void kernel_launch(void* const* d_in, const int* in_sizes, int n_in,
                              void* d_out, int out_size, void* d_ws, size_t ws_size,
                              hipStream_t stream) {
  const float* inputs = (const float*)d_in[0];
  const float* h0     = (const float*)d_in[1];
  const float* w_ih   = (const float*)d_in[2];
  const float* w_hh   = (const float*)d_in[3];
  const float* b_ih   = (const float*)d_in[4];
  const float* b_hh   = (const float*)d_in[5];

  float* outBase = (float*)d_out;
  float* hnBase  = outBase + (size_t)BATCH * SEQ * HDIM;

  // ws: h slabs (8 grp x 2 bufs x 32 KB = 512 KB) | flags 32 KB
  u32* ring = (u32*)d_ws;
  int* flags = (int*)(ring + (size_t)NGRP * 2 * SLAB_DW);
  const int nflags = NGRP * GSLOT * FPAD;

  init0<<<(nflags + 255) / 256, 256, 0, stream>>>(flags, nflags);
  init1<<<(BATCH * HDIM + 255) / 256, 256, 0, stream>>>(h0, ring);

  xproj_kernel<<<dim3(8, 256), 256, 0, stream>>>(inputs, w_ih, b_ih, b_hh, outBase);

  const float* wha = w_hh;
  float* oa = outBase;
  u32* ra = ring;
  int* fa = flags;
  void* args[4] = {&wha, &oa, &ra, &fa};
  (void)hipLaunchCooperativeKernel((const void*)rnn_scan, dim3(NBLK), dim3(576), args, 0, stream);

  copy_hn<<<256, 256, 0, stream>>>(outBase, hnBase);
}

// Round 17
// 1602.352 us; speedup vs baseline: 2.6908x; 2.6908x over previous
//
#include <hip/hip_runtime.h>
#include <hip/hip_bf16.h>
#include <stdint.h>

#define BATCH 64
#define SEQ   512
#define INDIM 1024
#define HDIM  1024
#define NBLK  256
#define NGRP  8      // 8 groups x 8 batch rows
#define GSLOT 32     // blocks per group, 32 hidden cols each
#define FPAD  16     // 64 B per flag
#define GBUF_U16 32768   // u16 per (group, buf): 32 k32 * 64 entries * 16
#define GBUF_DW  16384

typedef short bf16x8 __attribute__((ext_vector_type(8)));
typedef short s16x4  __attribute__((ext_vector_type(4)));
typedef float f32x4  __attribute__((ext_vector_type(4)));
typedef unsigned short u16;
typedef unsigned int   u32;
typedef u32 u32x4 __attribute__((ext_vector_type(4)));
typedef u16 u16x4 __attribute__((ext_vector_type(4)));

static __device__ __forceinline__ u16 f2bf(float x) {
  unsigned int u = __float_as_uint(x);
  u += 0x7fffu + ((u >> 16) & 1u);
  return (u16)(u >> 16);
}
static __device__ __forceinline__ float bf2f(u16 b) {
  return __uint_as_float(((unsigned int)b) << 16);
}

// device-coherent scalar load — proven flag-poll primitive (r9/r15)
static __device__ __forceinline__ int coh_ld_i32(const int* p) {
  int v;
  asm volatile("global_load_dword %0, %1, off sc0 sc1\n\t"
               "s_waitcnt vmcnt(0)"
               : "=&v"(v) : "v"(p) : "memory");
  return v;
}

static __device__ __forceinline__ void split4(float4 v, u16x4& hi, u16x4& lo) {
  hi.x = f2bf(v.x); lo.x = f2bf(v.x - bf2f(hi.x));
  hi.y = f2bf(v.y); lo.y = f2bf(v.y - bf2f(hi.y));
  hi.z = f2bf(v.z); lo.z = f2bf(v.z - bf2f(hi.z));
  hi.w = f2bf(v.w); lo.w = f2bf(v.w - bf2f(hi.w));
}
static __device__ __forceinline__ bf16x8 ld8(const u16* p) {
  s16x4 a = *(const s16x4*)p;
  s16x4 b = *(const s16x4*)(p + 4);
  return __builtin_shufflevector(a, b, 0, 1, 2, 3, 4, 5, 6, 7);
}

// ---- init0: poison h ring (bit15=1 everywhere), zero flags ----
__global__ void init0(u32* __restrict__ ws) {
  int i = blockIdx.x * blockDim.x + threadIdx.x;
  const int hdw = NGRP * 2 * GBUF_DW;   // 262144 dwords
  if (i < hdw) ws[i] = 0xFFFFFFFFu;
  else if (i < hdw + NGRP * GSLOT * FPAD) ws[i] = 0;
}

// ---- init1: pack h0 into buf0 of each group as interleaved dwords (hi|lo<<16) ----
// group g = rows [8g, 8g+8). dword idx (k32*64 + kg*16 + r)*8 + j holds
// h[8g + r][k32*32 + kg*8 + j]. Natural sign (t=0 skips validation).
__global__ void init1(const float* __restrict__ h0, u32* __restrict__ hw) {
  int i = blockIdx.x * blockDim.x + threadIdx.x;
  if (i < BATCH * HDIM) {
    int b = i >> 10, k = i & 1023;
    int g = b >> 3, r = b & 7;
    int k32 = k >> 5, kg = (k >> 3) & 3, j = k & 7;
    float x = h0[i];
    u16 hi = f2bf(x);
    u16 lo = f2bf(x - bf2f(hi));
    size_t di = (size_t)g * (2 * GBUF_DW) + (size_t)((k32 * 64 + kg * 16 + r) * 8 + j);
    hw[di] = (u32)hi | ((u32)lo << 16);
  }
}

// ---- xproj: xp = X @ Wih^T + bih + bhh via split-bf16 MFMA (into out) ----
__global__ __launch_bounds__(256) void xproj_kernel(const float* __restrict__ A,
                                                    const float* __restrict__ W,
                                                    const float* __restrict__ bih,
                                                    const float* __restrict__ bhh,
                                                    float* __restrict__ C) {
  __shared__ u16 Ah[4][128][12], Al[4][128][12], Bh[4][128][12], Bl[4][128][12];
  const int nb = blockIdx.x;
  const int mb = blockIdx.y;
  const int m_base = mb * 128, n_base = nb * 128;
  const int tid = (int)threadIdx.x;
  const int wid = tid >> 6, lane = tid & 63;
  const int wm = wid >> 1, wn = wid & 1;
  const int r = lane & 15, kg = lane >> 4;
  const int srow = tid >> 1;
  const int skq  = (tid & 1) * 16;

  const float* ap0 = A + (size_t)(m_base + srow) * INDIM + skq;
  const float* bp0 = W + (size_t)(n_base + srow) * INDIM + skq;

  f32x4 acc[4][4] = {};

  for (int k0 = 0; k0 < INDIM; k0 += 32) {
    float4 av[4], bv[4];
#pragma unroll
    for (int i = 0; i < 4; ++i) {
      av[i] = *(const float4*)(ap0 + k0 + i * 4);
      bv[i] = *(const float4*)(bp0 + k0 + i * 4);
    }
    __syncthreads();
#pragma unroll
    for (int i = 0; i < 4; ++i) {
      int kk = skq + i * 4;
      int kgw = kk >> 3, off = kk & 7;
      u16x4 hi, lo;
      split4(av[i], hi, lo);
      *(u16x4*)&Ah[kgw][srow][off] = hi;
      *(u16x4*)&Al[kgw][srow][off] = lo;
      split4(bv[i], hi, lo);
      *(u16x4*)&Bh[kgw][srow][off] = hi;
      *(u16x4*)&Bl[kgw][srow][off] = lo;
    }
    __syncthreads();

    bf16x8 ah[4], al[4], bhv[4], blv[4];
#pragma unroll
    for (int mf = 0; mf < 4; ++mf) {
      int row = wm * 64 + mf * 16 + r;
      ah[mf] = ld8(&Ah[kg][row][0]);
      al[mf] = ld8(&Al[kg][row][0]);
    }
#pragma unroll
    for (int nf = 0; nf < 4; ++nf) {
      int row = wn * 64 + nf * 16 + r;
      bhv[nf] = ld8(&Bh[kg][row][0]);
      blv[nf] = ld8(&Bl[kg][row][0]);
    }
#pragma unroll
    for (int mf = 0; mf < 4; ++mf)
#pragma unroll
      for (int nf = 0; nf < 4; ++nf) {
        acc[mf][nf] = __builtin_amdgcn_mfma_f32_16x16x32_bf16(ah[mf], bhv[nf], acc[mf][nf], 0, 0, 0);
        acc[mf][nf] = __builtin_amdgcn_mfma_f32_16x16x32_bf16(ah[mf], blv[nf], acc[mf][nf], 0, 0, 0);
        acc[mf][nf] = __builtin_amdgcn_mfma_f32_16x16x32_bf16(al[mf], bhv[nf], acc[mf][nf], 0, 0, 0);
      }
  }

#pragma unroll
  for (int nf = 0; nf < 4; ++nf) {
    int col = n_base + wn * 64 + nf * 16 + r;
    float bias = bih[col] + bhh[col];
#pragma unroll
    for (int mf = 0; mf < 4; ++mf) {
      int rowb = m_base + wm * 64 + mf * 16 + kg * 4;
#pragma unroll
      for (int q = 0; q < 4; ++q) {
        C[(size_t)(rowb + q) * HDIM + col] = acc[mf][nf][q] + bias;
      }
    }
  }
}

// ---- scan: r15 + {epi on wave8, no-ack tagged h exchange}. 576 threads. ----
// Block b: grp = b&7 (rows [8g,8g+8)), slot = b>>3 (cols [32s,32s+32)).
// Waves 0-7: pure consumers (poll flag hint, tagged load+validate, MFMA).
// Wave 8: epilogue + all HBM I/O. Depth-2 ring, tag = (t>>1)&1 in hi sign bit.
__global__ __launch_bounds__(576, 1) void rnn_scan(
    const float* __restrict__ Whh, float* __restrict__ out,
    u16* hbase, int* flags) {
  __shared__ u16 WH[32][2][64][8], WL[32][2][64][8];   // 128 KB
  __shared__ __align__(16) float red[2][8][2][8][20];  // 20 KB

  const int blk = (int)blockIdx.x;
  const int grp = blk & 7;
  const int slot = blk >> 3;
  const int n0 = slot * 32;
  const int tid = (int)threadIdx.x;
  const int wv = tid >> 6, lane = tid & 63;
  const int r = lane & 15, kg = lane >> 4;
  const bool zrow = r >= 8;

  // ---- one-time: stage Whh rows n0..n0+31 into LDS (576-thread grid-stride) ----
  for (int f4 = tid; f4 < 8192; f4 += 576) {
    int row = f4 >> 8;                  // 0..31
    int k0 = (f4 & 255) * 4;
    float4 v = *(const float4*)(Whh + (size_t)(n0 + row) * HDIM + k0);
    int k32 = k0 >> 5, kgg = (k0 >> 3) & 3, j = k0 & 7;
    int nt = row >> 4, ln = kgg * 16 + (row & 15);
    u16x4 hi, lo;
    split4(v, hi, lo);
    *(u16x4*)&WH[k32][nt][ln][j] = hi;
    *(u16x4*)&WL[k32][nt][ln][j] = lo;
  }
  __syncthreads();

  u16* const hb0 = hbase + (size_t)grp * (2 * GBUF_U16);
  u16* const hb1 = hb0 + GBUF_U16;
  int* const gflag = flags + grp * GSLOT * FPAD;
  const int* const pollp = gflag + ((wv & 7) * 4 + (lane & 3)) * FPAD;

  // epi / I/O geometry (wave 8): lane -> (row 0..7, col-quad ec4 = 0,4,..,28)
  const int erow = lane >> 3;
  const int ec4 = (lane & 7) * 4;
  float* const xpp = out + ((size_t)(grp * 8 + erow) * SEQ) * HDIM + n0 + ec4;
  f32x4 xf = {0.f, 0.f, 0.f, 0.f};
  if (wv == 8) {
    float4 xv = *(const float4*)xpp;   // xp(0)
    xf = (f32x4){xv.x, xv.y, xv.z, xv.w};
  }

  for (int t = 0; t < SEQ; ++t) {
    const int p2 = t & 1;

    if (wv < 8) {
      // ============ CONSUMERS ============
      const u16* hc = (t & 1) ? hb1 : hb0;
      const int rt = (t >> 1) & 1;                 // expected tag of h(t)
      const u32 rm = rt ? 0x80008000u : 0u;

      // (a) flag hint poll (own 4 producers)
      if (t > 0) {
        int v;
        do { v = coh_ld_i32(pollp); } while (!__all(v >= t));
      }

      // (b) tagged h-load: 8 x 16B, validate all 32 dword tags, retry if partial
      u32x4 P0, P1, P2, P3, P4, P5, P6, P7;
      if (!zrow) {
        const char* a0 = (const char*)hc + (size_t)((wv * 4) * 64 + lane) * 32;
        const char* a1 = a0 + 4096;
        for (;;) {
          asm volatile(
              "global_load_dwordx4 %0, %8, off sc0 sc1\n\t"
              "global_load_dwordx4 %1, %8, off offset:16 sc0 sc1\n\t"
              "global_load_dwordx4 %2, %8, off offset:2048 sc0 sc1\n\t"
              "global_load_dwordx4 %3, %8, off offset:2064 sc0 sc1\n\t"
              "global_load_dwordx4 %4, %9, off sc0 sc1\n\t"
              "global_load_dwordx4 %5, %9, off offset:16 sc0 sc1\n\t"
              "global_load_dwordx4 %6, %9, off offset:2048 sc0 sc1\n\t"
              "global_load_dwordx4 %7, %9, off offset:2064 sc0 sc1"
              : "=&v"(P0), "=&v"(P1), "=&v"(P2), "=&v"(P3),
                "=&v"(P4), "=&v"(P5), "=&v"(P6), "=&v"(P7)
              : "v"(a0), "v"(a1)
              : "memory");
          asm volatile("s_waitcnt vmcnt(0)"
              : "+v"(P0), "+v"(P1), "+v"(P2), "+v"(P3),
                "+v"(P4), "+v"(P5), "+v"(P6), "+v"(P7));
          if (t == 0) break;   // init-written, race-free, natural sign
          u32 m;
          if (rt) {
            m = P0[0] & P0[1] & P0[2] & P0[3] & P1[0] & P1[1] & P1[2] & P1[3]
              & P2[0] & P2[1] & P2[2] & P2[3] & P3[0] & P3[1] & P3[2] & P3[3]
              & P4[0] & P4[1] & P4[2] & P4[3] & P5[0] & P5[1] & P5[2] & P5[3]
              & P6[0] & P6[1] & P6[2] & P6[3] & P7[0] & P7[1] & P7[2] & P7[3];
          } else {
            m = P0[0] | P0[1] | P0[2] | P0[3] | P1[0] | P1[1] | P1[2] | P1[3]
              | P2[0] | P2[1] | P2[2] | P2[3] | P3[0] | P3[1] | P3[2] | P3[3]
              | P4[0] | P4[1] | P4[2] | P4[3] | P5[0] | P5[1] | P5[2] | P5[3]
              | P6[0] | P6[1] | P6[2] | P6[3] | P7[0] | P7[1] | P7[2] | P7[3];
          }
          bool ok = ((m >> 15) & 1u) == (u32)rt;
          if (__all((int)ok)) break;
        }
      } else {
        P0 = P1 = P2 = P3 = P4 = P5 = P6 = P7 = (u32x4){0, 0, 0, 0};
      }

      // (c) unpack (strip tag) + MFMA
      f32x4 acc0 = {0.f, 0.f, 0.f, 0.f};
      f32x4 acc1 = {0.f, 0.f, 0.f, 0.f};
#define DO_K32(i, QA, QB)                                                      \
      {                                                                        \
        u32 d0 = QA[0], d1 = QA[1], d2 = QA[2], d3 = QA[3];                    \
        u32 d4 = QB[0], d5 = QB[1], d6 = QB[2], d7 = QB[3];                    \
        union { u32 w[4]; bf16x8 v; } AH, AL;                                  \
        AH.w[0] = ((d0 & 0xFFFFu) | (d1 << 16)) ^ rm;                          \
        AH.w[1] = ((d2 & 0xFFFFu) | (d3 << 16)) ^ rm;                          \
        AH.w[2] = ((d4 & 0xFFFFu) | (d5 << 16)) ^ rm;                          \
        AH.w[3] = ((d6 & 0xFFFFu) | (d7 << 16)) ^ rm;                          \
        AL.w[0] = (d0 >> 16) | (d1 & 0xFFFF0000u);                             \
        AL.w[1] = (d2 >> 16) | (d3 & 0xFFFF0000u);                             \
        AL.w[2] = (d4 >> 16) | (d5 & 0xFFFF0000u);                             \
        AL.w[3] = (d6 >> 16) | (d7 & 0xFFFF0000u);                             \
        int k32 = wv * 4 + (i);                                                \
        bf16x8 b0h = *(const bf16x8*)&WH[k32][0][lane][0];                     \
        bf16x8 b0l = *(const bf16x8*)&WL[k32][0][lane][0];                     \
        bf16x8 b1h = *(const bf16x8*)&WH[k32][1][lane][0];                     \
        bf16x8 b1l = *(const bf16x8*)&WL[k32][1][lane][0];                     \
        acc0 = __builtin_amdgcn_mfma_f32_16x16x32_bf16(AH.v, b0h, acc0, 0, 0, 0); \
        acc0 = __builtin_amdgcn_mfma_f32_16x16x32_bf16(AH.v, b0l, acc0, 0, 0, 0); \
        acc0 = __builtin_amdgcn_mfma_f32_16x16x32_bf16(AL.v, b0h, acc0, 0, 0, 0); \
        acc1 = __builtin_amdgcn_mfma_f32_16x16x32_bf16(AH.v, b1h, acc1, 0, 0, 0); \
        acc1 = __builtin_amdgcn_mfma_f32_16x16x32_bf16(AH.v, b1l, acc1, 0, 0, 0); \
        acc1 = __builtin_amdgcn_mfma_f32_16x16x32_bf16(AL.v, b1h, acc1, 0, 0, 0); \
      }
      DO_K32(0, P0, P1)
      DO_K32(1, P2, P3)
      DO_K32(2, P4, P5)
      DO_K32(3, P6, P7)
#undef DO_K32

      // (d) K-reduction scratch. D: col = lane&15, row = kg*4+q (rows<8 only)
      if (kg < 2) {
#pragma unroll
        for (int q = 0; q < 4; ++q) {
          red[p2][wv][0][kg * 4 + q][r] = acc0[q];
          red[p2][wv][1][kg * 4 + q][r] = acc1[q];
        }
      }
      __syncthreads();   // B_t
    } else {
      // ============ WAVE 8: epilogue + all HBM I/O ============
      __syncthreads();   // B_t — red[p2] complete
      f32x4 s = xf;
      const int nt = ec4 >> 4, cl = ec4 & 15;
#pragma unroll
      for (int w = 0; w < 8; ++w) s += *(const f32x4*)&red[p2][w][nt][erow][cl];
#pragma unroll
      for (int j = 0; j < 4; ++j) s[j] = s[j] > 0.f ? s[j] : 0.f;

      // pack h(t+1) with epoch tag in hi sign bit
      const u16 wtag = (u16)((((t + 1) >> 1) & 1) << 15);
      u32x4 D;
#pragma unroll
      for (int j = 0; j < 4; ++j) {
        u16 hi = f2bf(s[j]);
        u16 lo = f2bf(s[j] - bf2f(hi));
        D[j] = (u32)(u16)(hi ^ wtag) | ((u32)lo << 16);
      }
      u16* hnx = (t & 1) ? hb0 : hb1;
      u32* hp = (u32*)hnx + (size_t)((slot * 64 + (ec4 >> 3) * 16 + erow) * 8 + (ec4 & 7));
      if (t == 1) {
        // one-time ack: closes the t=2 stale-h0-sign hazard
        asm volatile("global_store_dwordx4 %0, %1, off sc1\n\t"
                     "s_waitcnt vmcnt(0)"
                     :: "v"(hp), "v"(D) : "memory");
      } else {
        asm volatile("global_store_dwordx4 %0, %1, off sc1"
                     :: "v"(hp), "v"(D) : "memory");
      }
      if (lane == 0) {
        int* fp = gflag + slot * FPAD;
        int tv = t + 1;
        asm volatile("global_store_dword %0, %1, off sc0 sc1"
                     :: "v"(fp), "v"(tv) : "memory");
      }
      // out(t) + xp(t+1) — off the exchange path
      __builtin_nontemporal_store(s, (f32x4*)(xpp + (size_t)t * HDIM));
      if (t + 1 < SEQ) {
        float4 xv = *(const float4*)(xpp + (size_t)(t + 1) * HDIM);
        xf = (f32x4){xv.x, xv.y, xv.z, xv.w};
      }
    }
  }
}

// ---- h_n = outputs[:, SEQ-1, :] ----
__global__ void copy_hn(const float* __restrict__ out, float* __restrict__ hn) {
  int idx = blockIdx.x * blockDim.x + threadIdx.x;
  if (idx < BATCH * HDIM) {
    int b = idx >> 10, j = idx & 1023;
    hn[idx] = out[((size_t)b * SEQ + (SEQ - 1)) * (size_t)HDIM + j];
  }
}

extern "C" void kernel_launch(void* const* d_in, const int* in_sizes, int n_in,
                              void* d_out, int out_size, void* d_ws, size_t ws_size,
                              hipStream_t stream) {
  const float* inputs = (const float*)d_in[0];
  const float* h0     = (const float*)d_in[1];
  const float* w_ih   = (const float*)d_in[2];
  const float* w_hh   = (const float*)d_in[3];
  const float* b_ih   = (const float*)d_in[4];
  const float* b_hh   = (const float*)d_in[5];

  float* outBase = (float*)d_out;
  float* hnBase  = outBase + (size_t)BATCH * SEQ * HDIM;

  // ws: h ring (8 grp x 2 bufs x 64 KB = 1 MB) | flags 16 KB
  u16* hbase = (u16*)d_ws;
  int* flags = (int*)(hbase + (size_t)NGRP * 2 * GBUF_U16);

  const int init_n = NGRP * 2 * GBUF_DW + NGRP * GSLOT * FPAD;
  init0<<<(init_n + 255) / 256, 256, 0, stream>>>((u32*)d_ws);
  init1<<<(BATCH * HDIM + 255) / 256, 256, 0, stream>>>(h0, (u32*)hbase);

  xproj_kernel<<<dim3(8, 256), 256, 0, stream>>>(inputs, w_ih, b_ih, b_hh, outBase);

  const float* wha = w_hh;
  float* oa = outBase;
  u16* hba = hbase;
  int* fa = flags;
  void* args[4] = {&wha, &oa, &hba, &fa};
  (void)hipLaunchCooperativeKernel((const void*)rnn_scan, dim3(NBLK), dim3(576), args, 0, stream);

  copy_hn<<<256, 256, 0, stream>>>(outBase, hnBase);
}

// Round 18
// 1559.101 us; speedup vs baseline: 2.7655x; 1.0277x over previous
//
#include <hip/hip_runtime.h>
#include <hip/hip_bf16.h>
#include <stdint.h>

#define BATCH 64
#define SEQ   512
#define INDIM 1024
#define HDIM  1024
#define NBLK  256
#define NGRP  8      // 8 groups x 8 batch rows
#define GSLOT 32     // blocks per group, 32 hidden cols each
#define FPAD  16     // 64 B per flag
#define GBUF_U16 32768   // u16 per (group, buf): 32 k32 * 64 entries * 16
#define GBUF_DW  16384

typedef short bf16x8 __attribute__((ext_vector_type(8)));
typedef short s16x4  __attribute__((ext_vector_type(4)));
typedef float f32x4  __attribute__((ext_vector_type(4)));
typedef unsigned short u16;
typedef unsigned int   u32;
typedef u32 u32x4 __attribute__((ext_vector_type(4)));
typedef u16 u16x4 __attribute__((ext_vector_type(4)));

static __device__ __forceinline__ u16 f2bf(float x) {
  unsigned int u = __float_as_uint(x);
  u += 0x7fffu + ((u >> 16) & 1u);
  return (u16)(u >> 16);
}
static __device__ __forceinline__ float bf2f(u16 b) {
  return __uint_as_float(((unsigned int)b) << 16);
}

// device-coherent scalar load — proven flag-poll primitive (r9/r15)
static __device__ __forceinline__ int coh_ld_i32(const int* p) {
  int v;
  asm volatile("global_load_dword %0, %1, off sc0 sc1\n\t"
               "s_waitcnt vmcnt(0)"
               : "=&v"(v) : "v"(p) : "memory");
  return v;
}

static __device__ __forceinline__ void split4(float4 v, u16x4& hi, u16x4& lo) {
  hi.x = f2bf(v.x); lo.x = f2bf(v.x - bf2f(hi.x));
  hi.y = f2bf(v.y); lo.y = f2bf(v.y - bf2f(hi.y));
  hi.z = f2bf(v.z); lo.z = f2bf(v.z - bf2f(hi.z));
  hi.w = f2bf(v.w); lo.w = f2bf(v.w - bf2f(hi.w));
}
static __device__ __forceinline__ bf16x8 ld8(const u16* p) {
  s16x4 a = *(const s16x4*)p;
  s16x4 b = *(const s16x4*)(p + 4);
  return __builtin_shufflevector(a, b, 0, 1, 2, 3, 4, 5, 6, 7);
}

// ---- init0: zero flags ----
__global__ void init0(int* __restrict__ flags, int n) {
  int i = blockIdx.x * blockDim.x + threadIdx.x;
  if (i < n) flags[i] = 0;
}

// ---- init1: pack h0 into buf0 of each group as interleaved dwords (hi|lo<<16) ----
// group g = rows [8g, 8g+8). dword idx (k32*64 + kg*16 + r)*8 + j holds
// h[8g + r][k32*32 + kg*8 + j]. Entries r=8..15 never read (zrow).
__global__ void init1(const float* __restrict__ h0, u32* __restrict__ hw) {
  int i = blockIdx.x * blockDim.x + threadIdx.x;
  if (i < BATCH * HDIM) {
    int b = i >> 10, k = i & 1023;
    int g = b >> 3, r = b & 7;
    int k32 = k >> 5, kg = (k >> 3) & 3, j = k & 7;
    float x = h0[i];
    u16 hi = f2bf(x);
    u16 lo = f2bf(x - bf2f(hi));
    size_t di = (size_t)g * (2 * GBUF_DW) + (size_t)((k32 * 64 + kg * 16 + r) * 8 + j);
    hw[di] = (u32)hi | ((u32)lo << 16);
  }
}

// ---- xproj: xp = X @ Wih^T + bih + bhh via split-bf16 MFMA (into out) ----
__global__ __launch_bounds__(256) void xproj_kernel(const float* __restrict__ A,
                                                    const float* __restrict__ W,
                                                    const float* __restrict__ bih,
                                                    const float* __restrict__ bhh,
                                                    float* __restrict__ C) {
  __shared__ u16 Ah[4][128][12], Al[4][128][12], Bh[4][128][12], Bl[4][128][12];
  const int nb = blockIdx.x;
  const int mb = blockIdx.y;
  const int m_base = mb * 128, n_base = nb * 128;
  const int tid = (int)threadIdx.x;
  const int wid = tid >> 6, lane = tid & 63;
  const int wm = wid >> 1, wn = wid & 1;
  const int r = lane & 15, kg = lane >> 4;
  const int srow = tid >> 1;
  const int skq  = (tid & 1) * 16;

  const float* ap0 = A + (size_t)(m_base + srow) * INDIM + skq;
  const float* bp0 = W + (size_t)(n_base + srow) * INDIM + skq;

  f32x4 acc[4][4] = {};

  for (int k0 = 0; k0 < INDIM; k0 += 32) {
    float4 av[4], bv[4];
#pragma unroll
    for (int i = 0; i < 4; ++i) {
      av[i] = *(const float4*)(ap0 + k0 + i * 4);
      bv[i] = *(const float4*)(bp0 + k0 + i * 4);
    }
    __syncthreads();
#pragma unroll
    for (int i = 0; i < 4; ++i) {
      int kk = skq + i * 4;
      int kgw = kk >> 3, off = kk & 7;
      u16x4 hi, lo;
      split4(av[i], hi, lo);
      *(u16x4*)&Ah[kgw][srow][off] = hi;
      *(u16x4*)&Al[kgw][srow][off] = lo;
      split4(bv[i], hi, lo);
      *(u16x4*)&Bh[kgw][srow][off] = hi;
      *(u16x4*)&Bl[kgw][srow][off] = lo;
    }
    __syncthreads();

    bf16x8 ah[4], al[4], bhv[4], blv[4];
#pragma unroll
    for (int mf = 0; mf < 4; ++mf) {
      int row = wm * 64 + mf * 16 + r;
      ah[mf] = ld8(&Ah[kg][row][0]);
      al[mf] = ld8(&Al[kg][row][0]);
    }
#pragma unroll
    for (int nf = 0; nf < 4; ++nf) {
      int row = wn * 64 + nf * 16 + r;
      bhv[nf] = ld8(&Bh[kg][row][0]);
      blv[nf] = ld8(&Bl[kg][row][0]);
    }
#pragma unroll
    for (int mf = 0; mf < 4; ++mf)
#pragma unroll
      for (int nf = 0; nf < 4; ++nf) {
        acc[mf][nf] = __builtin_amdgcn_mfma_f32_16x16x32_bf16(ah[mf], bhv[nf], acc[mf][nf], 0, 0, 0);
        acc[mf][nf] = __builtin_amdgcn_mfma_f32_16x16x32_bf16(ah[mf], blv[nf], acc[mf][nf], 0, 0, 0);
        acc[mf][nf] = __builtin_amdgcn_mfma_f32_16x16x32_bf16(al[mf], bhv[nf], acc[mf][nf], 0, 0, 0);
      }
  }

#pragma unroll
  for (int nf = 0; nf < 4; ++nf) {
    int col = n_base + wn * 64 + nf * 16 + r;
    float bias = bih[col] + bhh[col];
#pragma unroll
    for (int mf = 0; mf < 4; ++mf) {
      int rowb = m_base + wm * 64 + mf * 16 + kg * 4;
#pragma unroll
      for (int q = 0; q < 4; ++q) {
        C[(size_t)(rowb + q) * HDIM + col] = acc[mf][nf][q] + bias;
      }
    }
  }
}

// ---- scan: r15 structure (best measured) + fused h_n tail. 576 threads. ----
// Block b: grp = b&7 (rows [8g,8g+8)), slot = b>>3 (cols [32s,32s+32)).
// Waves 0-7: consumers (K=128 each, poll own 4 producer flags).
// Wave 0: epi (LDS-only inputs + sc1 h-store + flag). Wave 8: all HBM I/O.
__global__ __launch_bounds__(576, 1) void rnn_scan(
    const float* __restrict__ Whh, float* __restrict__ out,
    u16* hbase, int* flags, float* __restrict__ hn) {
  __shared__ u16 WH[32][2][64][8], WL[32][2][64][8];   // 128 KB
  __shared__ __align__(16) float red[2][8][2][8][20];  // 20 KB
  __shared__ __align__(16) float xfbuf[2][8][32];      // 2 KB
  __shared__ __align__(16) float sbuf[2][8][32];       // 2 KB

  const int blk = (int)blockIdx.x;
  const int grp = blk & 7;
  const int slot = blk >> 3;
  const int n0 = slot * 32;
  const int tid = (int)threadIdx.x;
  const int wv = tid >> 6, lane = tid & 63;
  const int r = lane & 15, kg = lane >> 4;
  const bool zrow = r >= 8;

  // ---- one-time: stage Whh rows n0..n0+31 into LDS (576-thread grid-stride) ----
  for (int f4 = tid; f4 < 8192; f4 += 576) {
    int row = f4 >> 8;                  // 0..31
    int k0 = (f4 & 255) * 4;
    float4 v = *(const float4*)(Whh + (size_t)(n0 + row) * HDIM + k0);
    int k32 = k0 >> 5, kgg = (k0 >> 3) & 3, j = k0 & 7;
    int nt = row >> 4, ln = kgg * 16 + (row & 15);
    u16x4 hi, lo;
    split4(v, hi, lo);
    *(u16x4*)&WH[k32][nt][ln][j] = hi;
    *(u16x4*)&WL[k32][nt][ln][j] = lo;
  }
  __syncthreads();

  u16* const hb0 = hbase + (size_t)grp * (2 * GBUF_U16);
  u16* const hb1 = hb0 + GBUF_U16;
  int* const gflag = flags + grp * GSLOT * FPAD;
  const int* const pollp = gflag + ((wv & 7) * 4 + (lane & 3)) * FPAD;

  // epi / I/O geometry: lane -> (row 0..7, col-quad ec4 = 0,4,..,28)
  const int erow = lane >> 3;
  const int ec4 = (lane & 7) * 4;
  float* const xpp = out + ((size_t)(grp * 8 + erow) * SEQ) * HDIM + n0 + ec4;

  for (int t = 0; t < SEQ; ++t) {
    const int p2 = t & 1;

    if (wv < 8) {
      // ============ CONSUMERS (r9 verbatim) ============
      const u16* hc = (t & 1) ? hb1 : hb0;

      // (a) per-wave poll of own 4 producers
      if (t > 0) {
        int v;
        do { v = coh_ld_i32(pollp); } while (!__all(v >= t));
      }

      // (b) h-load: 8 x 16B system-scope loads
      u32x4 P0, P1, P2, P3, P4, P5, P6, P7;
      if (!zrow) {
        const char* a0 = (const char*)hc + (size_t)((wv * 4) * 64 + lane) * 32;
        const char* a1 = a0 + 4096;
        asm volatile(
            "global_load_dwordx4 %0, %8, off sc0 sc1\n\t"
            "global_load_dwordx4 %1, %8, off offset:16 sc0 sc1\n\t"
            "global_load_dwordx4 %2, %8, off offset:2048 sc0 sc1\n\t"
            "global_load_dwordx4 %3, %8, off offset:2064 sc0 sc1\n\t"
            "global_load_dwordx4 %4, %9, off sc0 sc1\n\t"
            "global_load_dwordx4 %5, %9, off offset:16 sc0 sc1\n\t"
            "global_load_dwordx4 %6, %9, off offset:2048 sc0 sc1\n\t"
            "global_load_dwordx4 %7, %9, off offset:2064 sc0 sc1"
            : "=&v"(P0), "=&v"(P1), "=&v"(P2), "=&v"(P3),
              "=&v"(P4), "=&v"(P5), "=&v"(P6), "=&v"(P7)
            : "v"(a0), "v"(a1)
            : "memory");
        asm volatile("s_waitcnt vmcnt(0)"
            : "+v"(P0), "+v"(P1), "+v"(P2), "+v"(P3),
              "+v"(P4), "+v"(P5), "+v"(P6), "+v"(P7));
      } else {
        P0 = P1 = P2 = P3 = P4 = P5 = P6 = P7 = (u32x4){0, 0, 0, 0};
      }

      // (c) unpack + MFMA
      f32x4 acc0 = {0.f, 0.f, 0.f, 0.f};
      f32x4 acc1 = {0.f, 0.f, 0.f, 0.f};
#define DO_K32(i, QA, QB)                                                      \
      {                                                                        \
        u32 d0 = QA[0], d1 = QA[1], d2 = QA[2], d3 = QA[3];                    \
        u32 d4 = QB[0], d5 = QB[1], d6 = QB[2], d7 = QB[3];                    \
        union { u32 w[4]; bf16x8 v; } AH, AL;                                  \
        AH.w[0] = (d0 & 0xFFFFu) | (d1 << 16);                                 \
        AH.w[1] = (d2 & 0xFFFFu) | (d3 << 16);                                 \
        AH.w[2] = (d4 & 0xFFFFu) | (d5 << 16);                                 \
        AH.w[3] = (d6 & 0xFFFFu) | (d7 << 16);                                 \
        AL.w[0] = (d0 >> 16) | (d1 & 0xFFFF0000u);                             \
        AL.w[1] = (d2 >> 16) | (d3 & 0xFFFF0000u);                             \
        AL.w[2] = (d4 >> 16) | (d5 & 0xFFFF0000u);                             \
        AL.w[3] = (d6 >> 16) | (d7 & 0xFFFF0000u);                             \
        int k32 = wv * 4 + (i);                                                \
        bf16x8 b0h = *(const bf16x8*)&WH[k32][0][lane][0];                     \
        bf16x8 b0l = *(const bf16x8*)&WL[k32][0][lane][0];                     \
        bf16x8 b1h = *(const bf16x8*)&WH[k32][1][lane][0];                     \
        bf16x8 b1l = *(const bf16x8*)&WL[k32][1][lane][0];                     \
        acc0 = __builtin_amdgcn_mfma_f32_16x16x32_bf16(AH.v, b0h, acc0, 0, 0, 0); \
        acc0 = __builtin_amdgcn_mfma_f32_16x16x32_bf16(AH.v, b0l, acc0, 0, 0, 0); \
        acc0 = __builtin_amdgcn_mfma_f32_16x16x32_bf16(AL.v, b0h, acc0, 0, 0, 0); \
        acc1 = __builtin_amdgcn_mfma_f32_16x16x32_bf16(AH.v, b1h, acc1, 0, 0, 0); \
        acc1 = __builtin_amdgcn_mfma_f32_16x16x32_bf16(AH.v, b1l, acc1, 0, 0, 0); \
        acc1 = __builtin_amdgcn_mfma_f32_16x16x32_bf16(AL.v, b1h, acc1, 0, 0, 0); \
      }
      DO_K32(0, P0, P1)
      DO_K32(1, P2, P3)
      DO_K32(2, P4, P5)
      DO_K32(3, P6, P7)
#undef DO_K32

      // (d) K-reduction scratch. D: col = lane&15, row = kg*4+q (rows<8 only)
      if (kg < 2) {
#pragma unroll
        for (int q = 0; q < 4; ++q) {
          red[p2][wv][0][kg * 4 + q][r] = acc0[q];
          red[p2][wv][1][kg * 4 + q][r] = acc1[q];
        }
      }
      __syncthreads();   // B_t

      if (wv == 0) {
        // ============ EPILOGUE (LDS-only inputs; sc1 h-store; flag) ============
        f32x4 s = *(const f32x4*)&xfbuf[p2][erow][ec4];
        const int nt = ec4 >> 4, cl = ec4 & 15;
#pragma unroll
        for (int w = 0; w < 8; ++w) s += *(const f32x4*)&red[p2][w][nt][erow][cl];
#pragma unroll
        for (int j = 0; j < 4; ++j) s[j] = s[j] > 0.f ? s[j] : 0.f;
        *(f32x4*)&sbuf[p2][erow][ec4] = s;

        u32x4 D;
#pragma unroll
        for (int j = 0; j < 4; ++j) {
          u16 hi = f2bf(s[j]);
          u16 lo = f2bf(s[j] - bf2f(hi));
          D[j] = (u32)hi | ((u32)lo << 16);
        }
        u16* hnx = (t & 1) ? hb0 : hb1;
        u32* hp = (u32*)hnx + (size_t)((slot * 64 + (ec4 >> 3) * 16 + erow) * 8 + (ec4 & 7));
        // agent-scope store (MALL-coherent, r12-proven) + ack, then flag
        asm volatile("global_store_dwordx4 %0, %1, off sc1\n\t"
                     "s_waitcnt vmcnt(0)"
                     :: "v"(hp), "v"(D) : "memory");
        if (lane == 0) {
          int* fp = gflag + slot * FPAD;
          int tv = t + 1;
          asm volatile("global_store_dword %0, %1, off sc0 sc1"
                       :: "v"(fp), "v"(tv) : "memory");
        }
      }
    } else {
      // ============ WAVE 8: all HBM I/O ============
      // out(t-2) from sbuf[(t-2)&1] == sbuf[t&1] (written before B_{t-1})
      if (t >= 2) {
        f32x4 sv = *(const f32x4*)&sbuf[p2][erow][ec4];
        __builtin_nontemporal_store(sv, (f32x4*)(xpp + (size_t)(t - 2) * HDIM));
      }
      // xp(t) -> xfbuf[t&1] (epi(t) reads it after B_t)
      float4 xv = *(const float4*)(xpp + (size_t)t * HDIM);
      f32x4 xr = {xv.x, xv.y, xv.z, xv.w};
      *(f32x4*)&xfbuf[p2][erow][ec4] = xr;
      __syncthreads();   // B_t
    }
  }

  // tail: out(SEQ-2), out(SEQ-1), and h_n = outputs[:, SEQ-1, :]
  __syncthreads();
  if (wv == 8) {
    f32x4 s2 = *(const f32x4*)&sbuf[(SEQ - 2) & 1][erow][ec4];
    __builtin_nontemporal_store(s2, (f32x4*)(xpp + (size_t)(SEQ - 2) * HDIM));
    f32x4 s1 = *(const f32x4*)&sbuf[(SEQ - 1) & 1][erow][ec4];
    __builtin_nontemporal_store(s1, (f32x4*)(xpp + (size_t)(SEQ - 1) * HDIM));
    __builtin_nontemporal_store(s1,
        (f32x4*)(hn + (size_t)(grp * 8 + erow) * HDIM + n0 + ec4));
  }
}

extern "C" void kernel_launch(void* const* d_in, const int* in_sizes, int n_in,
                              void* d_out, int out_size, void* d_ws, size_t ws_size,
                              hipStream_t stream) {
  const float* inputs = (const float*)d_in[0];
  const float* h0     = (const float*)d_in[1];
  const float* w_ih   = (const float*)d_in[2];
  const float* w_hh   = (const float*)d_in[3];
  const float* b_ih   = (const float*)d_in[4];
  const float* b_hh   = (const float*)d_in[5];

  float* outBase = (float*)d_out;
  float* hnBase  = outBase + (size_t)BATCH * SEQ * HDIM;

  // ws: h ring (8 grp x 2 bufs x 64 KB = 1 MB) | flags 16 KB
  u16* hbase = (u16*)d_ws;
  int* flags = (int*)(hbase + (size_t)NGRP * 2 * GBUF_U16);
  const int nflags = NGRP * GSLOT * FPAD;

  init0<<<(nflags + 255) / 256, 256, 0, stream>>>(flags, nflags);
  init1<<<(BATCH * HDIM + 255) / 256, 256, 0, stream>>>(h0, (u32*)hbase);

  xproj_kernel<<<dim3(8, 256), 256, 0, stream>>>(inputs, w_ih, b_ih, b_hh, outBase);

  const float* wha = w_hh;
  float* oa = outBase;
  u16* hba = hbase;
  int* fa = flags;
  float* hna = hnBase;
  void* args[5] = {&wha, &oa, &hba, &fa, &hna};
  (void)hipLaunchCooperativeKernel((const void*)rnn_scan, dim3(NBLK), dim3(576), args, 0, stream);
}